// Round 1
// baseline (786.352 us; speedup 1.0000x reference)
//
#include <hip/hip_runtime.h>
#include <math.h>

#define EPSV 1e-8f

// d_out layout (floats): ntm_out[0], memory[65536], read_out[33619968],
// new_read_w[33685504], new_write_w[35782656]
#define O_MEM 65536
#define O_RO  33619968
#define O_NRW 33685504
#define O_NWW 35782656

__device__ __forceinline__ float sp_(float x){ return fmaxf(x,0.f) + log1pf(expf(-fabsf(x))); }
__device__ __forceinline__ float sg_(float x){ return 1.f/(1.f+expf(-x)); }

// ---------------- small GEMMs ----------------

// ctrl[b,c] = concat(ext[b], past_readings[b]) @ ctrl_W + ctrl_b
__global__ void k1_ctrl(const float* __restrict__ ext, const float* __restrict__ prd,
                        const float* __restrict__ W, const float* __restrict__ bias,
                        float* __restrict__ ctrl){
  __shared__ float ins[2][512];
  int t = threadIdx.x; int b0 = blockIdx.x*2;
  for (int i = t; i < 1024; i += 256){
    int bb = i >> 9, i2 = i & 511;
    ins[bb][i2] = (i2 < 256) ? ext[(b0+bb)*256 + i2] : prd[(b0+bb)*256 + (i2-256)];
  }
  __syncthreads();
  float a00=0.f,a01=0.f,a10=0.f,a11=0.f;
  for (int i=0;i<512;i++){
    float w0 = W[i*512 + t];
    float w1 = W[i*512 + t + 256];
    float x0 = ins[0][i], x1 = ins[1][i];
    a00 = fmaf(x0,w0,a00); a01 = fmaf(x0,w1,a01);
    a10 = fmaf(x1,w0,a10); a11 = fmaf(x1,w1,a11);
  }
  ctrl[b0*512 + t]           = a00 + bias[t];
  ctrl[b0*512 + t + 256]     = a01 + bias[t+256];
  ctrl[(b0+1)*512 + t]       = a10 + bias[t];
  ctrl[(b0+1)*512 + t + 256] = a11 + bias[t+256];
}

// rp[h,b,0:70] and wp[h,b,0:198] projections
__global__ void k2_proj(const float* __restrict__ ctrl,
                        const float* __restrict__ rW, const float* __restrict__ rB,
                        const float* __restrict__ wW, const float* __restrict__ wB,
                        float* __restrict__ rp, float* __restrict__ wp){
  __shared__ float cs[2][512];
  int t = threadIdx.x; int b0 = blockIdx.x*2;
  for (int i=t; i<1024; i+=512){ int bb=i>>9, i2=i&511; cs[bb][i2] = ctrl[(b0+bb)*512+i2]; }
  __syncthreads();
  for (int c = t; c < 1072; c += 512){
    const float* Wc; int stride; float bv; float* dst0; float* dst1;
    if (c < 280){
      int h=c/70, j=c%70;
      Wc = rW + (size_t)h*512*70 + j; stride = 70; bv = rB[h*70+j];
      dst0 = rp + ((size_t)(h*256)+b0)*70 + j; dst1 = dst0 + 70;
    } else {
      int c2=c-280; int h=c2/198, j=c2%198;
      Wc = wW + (size_t)h*512*198 + j; stride = 198; bv = wB[h*198+j];
      dst0 = wp + ((size_t)(h*256)+b0)*198 + j; dst1 = dst0 + 198;
    }
    float a0=0.f,a1=0.f;
    for (int i=0;i<512;i++){
      float w = Wc[(size_t)i*stride];
      a0 = fmaf(cs[0][i],w,a0); a1 = fmaf(cs[1][i],w,a1);
    }
    *dst0 = a0+bv; *dst1 = a1+bv;
  }
}

// ntm_out = concat(ctrl, read_out) @ out_W + out_b
__global__ void k3_out(const float* __restrict__ ctrl, const float* __restrict__ oW,
                       const float* __restrict__ oB, float* __restrict__ out){
  __shared__ float cr[2][768];
  int t = threadIdx.x; int b0 = blockIdx.x*2;
  for (int i=t;i<1536;i+=256){
    int bb=i/768, i2=i%768;
    cr[bb][i2] = (i2<512) ? ctrl[(b0+bb)*512+i2] : out[O_RO + (b0+bb)*256 + (i2-512)];
  }
  __syncthreads();
  float a0=0.f,a1=0.f;
  for (int i=0;i<768;i++){
    float w = oW[i*256+t];
    a0=fmaf(cr[0][i],w,a0); a1=fmaf(cr[1][i],w,a1);
  }
  out[(size_t)b0*256 + t]     = a0 + oB[t];
  out[(size_t)(b0+1)*256 + t] = a1 + oB[t];
}

// ---------------- mega kernel ----------------

__device__ __forceinline__ float blockMax(float v, float* red){
  #pragma unroll
  for (int o=32;o;o>>=1) v = fmaxf(v, __shfl_down(v,o,64));
  __syncthreads();
  if ((threadIdx.x & 63) == 0) red[threadIdx.x>>6] = v;
  __syncthreads();
  return fmaxf(fmaxf(red[0],red[1]), fmaxf(red[2],red[3]));
}
__device__ __forceinline__ float blockSum(float v, float* red){
  #pragma unroll
  for (int o=32;o;o>>=1) v += __shfl_down(v,o,64);
  __syncthreads();
  if ((threadIdx.x & 63) == 0) red[threadIdx.x>>6] = v;
  __syncthreads();
  return red[0]+red[1]+red[2]+red[3];
}

// NTM addressing over one slot c[2048] (holds cos-sim on entry, final w on exit)
__device__ void addressing(float* c, const float* __restrict__ wprev, float* __restrict__ wout,
                           float beta, float g, float s0, float s1, float s2, float gam,
                           float* red, int t){
  int base = t*8;
  float lv[8];
  float mx = -1e30f;
  #pragma unroll
  for (int i=0;i<8;i++){ lv[i] = beta*c[base+i]; mx = fmaxf(mx, lv[i]); }
  mx = blockMax(mx, red);
  float sm = 0.f;
  #pragma unroll
  for (int i=0;i<8;i++){ lv[i] = expf(lv[i]-mx); sm += lv[i]; }
  sm = blockSum(sm, red);
  float inv = 1.f/sm;
  float gi = 1.f - g;
  #pragma unroll
  for (int i=0;i<8;i++){ lv[i] = g*lv[i]*inv + gi*wprev[base+i]; }
  #pragma unroll
  for (int i=0;i<8;i++) c[base+i] = lv[i];   // own range only
  __syncthreads();
  float left  = c[(base+2047)&2047];
  float right = c[(base+8)&2047];
  __syncthreads();                           // halos read before overwrite
  float pw[8]; float ps=0.f;
  #pragma unroll
  for (int i=0;i<8;i++){
    float wm1 = (i==0)? left  : lv[i-1];
    float wp1 = (i==7)? right : lv[i+1];
    float wsv = s0*wp1 + s1*lv[i] + s2*wm1;
    float p = expf(gam * logf(wsv + EPSV));
    pw[i]=p; ps+=p;
  }
  ps = blockSum(ps, red);
  float invp = 1.f/ps;
  #pragma unroll
  for (int i=0;i<8;i++){ float w = pw[i]*invp; c[base+i]=w; wout[base+i]=w; }
  __syncthreads();
}

// one sweep over memory[b]: stage tile -> (optional read-accumulate on raw rows)
// -> per-row replay of NUPD write updates -> cos/norm or final writeback
template<int NUPD, int NCOS, int CS0, int KS0, bool READS, bool FINAL>
__device__ __forceinline__ void mem_pass(const float4* __restrict__ gmb,
    float* tile, float (*slots)[2048],
    const float* kr, const float* kw, const float* er, const float* aw, const float* sKn,
    float4* racc, float4* __restrict__ goutMem, int t)
{
  const int wsl[4] = {4,5,0,1};  // LDS slots holding w_w0..w_w3
  for (int tl=0; tl<8; tl++){
    __syncthreads();
    const float4* src = gmb + tl*4096;
    #pragma unroll
    for (int j=0;j<16;j++){
      int idx = j*256 + t;
      float4 v = src[idx];
      int row = idx >> 4;
      int col = (idx & 15) << 2;
      *(float4*)&tile[row*68 + col] = v;
      if (READS){
        int grow = tl*256 + row;
        #pragma unroll
        for (int h=0;h<4;h++){
          float w = slots[h][grow];
          racc[h].x = fmaf(w, v.x, racc[h].x);
          racc[h].y = fmaf(w, v.y, racc[h].y);
          racc[h].z = fmaf(w, v.z, racc[h].z);
          racc[h].w = fmaf(w, v.w, racc[h].w);
        }
      }
    }
    __syncthreads();
    int grow = tl*256 + t;
    float wu[NUPD>0?NUPD:1];
    #pragma unroll
    for (int h=0;h<NUPD;h++) wu[h] = slots[wsl[h]][grow];
    float nrm = 0.f;
    float acc[NCOS>0?NCOS:1];
    #pragma unroll
    for (int c=0;c<NCOS;c++) acc[c]=0.f;
    #pragma unroll
    for (int j=0;j<16;j++){
      float4 v = *(const float4*)&tile[t*68 + (j<<2)];
      #pragma unroll
      for (int h=0;h<NUPD;h++){
        float w = wu[h];
        const float4 e = *(const float4*)&er[h*64 + (j<<2)];
        const float4 a = *(const float4*)&aw[h*64 + (j<<2)];
        v.x = fmaf(w, a.x, v.x*(1.f - w*e.x));
        v.y = fmaf(w, a.y, v.y*(1.f - w*e.y));
        v.z = fmaf(w, a.z, v.z*(1.f - w*e.z));
        v.w = fmaf(w, a.w, v.w*(1.f - w*e.w));
      }
      if (!FINAL){
        nrm = fmaf(v.x,v.x, fmaf(v.y,v.y, fmaf(v.z,v.z, fmaf(v.w,v.w, nrm))));
        #pragma unroll
        for (int c=0;c<NCOS;c++){
          int ks = (NCOS==5)? c : KS0;
          const float* kb = (ks<4)? (kr + ks*64) : (kw + (ks-4)*64);
          const float4 k = *(const float4*)&kb[j<<2];
          acc[c] = fmaf(v.x,k.x, fmaf(v.y,k.y, fmaf(v.z,k.z, fmaf(v.w,k.w, acc[c]))));
        }
      } else {
        *(float4*)&tile[t*68 + (j<<2)] = v;
      }
    }
    if (!FINAL){
      float mn = sqrtf(nrm);
      #pragma unroll
      for (int c=0;c<NCOS;c++){
        int sl = (NCOS==5)? c : CS0;
        int ks = (NCOS==5)? c : KS0;
        slots[sl][grow] = acc[c] / (mn*sKn[ks] + EPSV);
      }
    } else {
      __syncthreads();
      #pragma unroll
      for (int j=0;j<16;j++){
        int idx = j*256 + t;
        int row = idx >> 4;
        int col = (idx & 15) << 2;
        goutMem[tl*4096 + idx] = *(const float4*)&tile[row*68 + col];
      }
    }
  }
}

__global__ __launch_bounds__(256,1) void mega_kernel(
    const float* __restrict__ mem0, const float* __restrict__ prw, const float* __restrict__ pww,
    const float* __restrict__ rp, const float* __restrict__ wp, float* __restrict__ out)
{
  const int b = blockIdx.x, t = threadIdx.x;
  __shared__ float slots[6][2048];     // 48 KB: 0-3 cos_r->w_r (then cos_w2->w_w2, cos_w3->w_w3); 4,5: w_w0,w_w1
  __shared__ float tile[256*68];       // 68 KB (also reads-reduce scratch)
  __shared__ float kr[256], kw[256], er[256], aw[256];
  __shared__ float sBeta[8], sG[8], sGam[8], sKn[8], sS0[8], sS1[8], sS2[8];
  __shared__ float red[8];

  { // activations: idx 0-3 read heads, 4-7 write heads
    int h = t>>6, m = t&63;
    kr[t] = rp[((size_t)h*256 + b)*70 + m];
    const float* wph = wp + ((size_t)h*256 + b)*198;
    kw[t] = wph[m];
    er[t] = sg_(wph[70+m]);
    aw[t] = tanhf(wph[134+m]);
    if (t < 8){
      int hh = t & 3;
      const float* p = (t>=4) ? (wp + ((size_t)hh*256+b)*198) : (rp + ((size_t)hh*256+b)*70);
      sBeta[t] = sp_(p[64]);
      sG[t]    = sg_(p[65]);
      float a0=p[66], a1=p[67], a2=p[68];
      float mx = fmaxf(a0, fmaxf(a1,a2));
      float e0=expf(a0-mx), e1=expf(a1-mx), e2=expf(a2-mx);
      float inv = 1.f/(e0+e1+e2);
      sS0[t]=e0*inv; sS1[t]=e1*inv; sS2[t]=e2*inv;
      sGam[t]  = 1.f + sp_(p[69]);
    }
  }
  __syncthreads();
  if (t < 8){
    const float* kv = (t>=4) ? (kw + (t&3)*64) : (kr + (t&3)*64);
    float s=0.f;
    for (int m=0;m<64;m++) s = fmaf(kv[m],kv[m],s);
    sKn[t] = sqrtf(s);
  }
  __syncthreads();

  const float4* gmb = (const float4*)mem0 + (size_t)b*32768;
  float4 racc[4];
  #pragma unroll
  for (int h=0;h<4;h++) racc[h] = make_float4(0.f,0.f,0.f,0.f);

  // Pass A: norm + cos for read heads 0-3 (slots 0-3) and write head 0 (slot 4)
  mem_pass<0,5,0,0,false,false>(gmb, tile, slots, kr,kw,er,aw,sKn, racc, nullptr, t);
  __syncthreads();

  #pragma unroll 1
  for (int h=0;h<4;h++)
    addressing(slots[h], prw + ((size_t)h*256+b)*2048, out + O_NRW + ((size_t)h*256+b)*2048,
               sBeta[h], sG[h], sS0[h], sS1[h], sS2[h], sGam[h], red, t);
  addressing(slots[4], pww + (size_t)b*2048, out + O_NWW + (size_t)b*2048,
             sBeta[4], sG[4], sS0[4], sS1[4], sS2[4], sGam[4], red, t);

  // Pass 1: read-vector accumulation (raw rows) + update0 -> cos_w1 (slot 5)
  mem_pass<1,1,5,5,true,false>(gmb, tile, slots, kr,kw,er,aw,sKn, racc, nullptr, t);
  __syncthreads();
  { // reduce racc (per (q=t>>4, m4=t&15) partials) -> read_out
    float4* scr = (float4*)tile;
    int q = t>>4, m4 = t&15;
    #pragma unroll
    for (int h=0;h<4;h++) scr[(q*4+h)*16 + m4] = racc[h];
    __syncthreads();
    int h = t>>6, m = t&63;
    float s = 0.f;
    for (int q2=0;q2<16;q2++) s += tile[((q2*4+h)*16 + (m>>2))*4 + (m&3)];
    out[O_RO + (size_t)b*256 + t] = s;
  }
  addressing(slots[5], pww + ((size_t)256+b)*2048, out + O_NWW + ((size_t)256+b)*2048,
             sBeta[5], sG[5], sS0[5], sS1[5], sS2[5], sGam[5], red, t);

  // Pass 2: updates {0,1} -> cos_w2 (slot 0, freed)
  mem_pass<2,1,0,6,false,false>(gmb, tile, slots, kr,kw,er,aw,sKn, racc, nullptr, t);
  __syncthreads();
  addressing(slots[0], pww + ((size_t)512+b)*2048, out + O_NWW + ((size_t)512+b)*2048,
             sBeta[6], sG[6], sS0[6], sS1[6], sS2[6], sGam[6], red, t);

  // Pass 3: updates {0,1,2} -> cos_w3 (slot 1)
  mem_pass<3,1,1,7,false,false>(gmb, tile, slots, kr,kw,er,aw,sKn, racc, nullptr, t);
  __syncthreads();
  addressing(slots[1], pww + ((size_t)768+b)*2048, out + O_NWW + ((size_t)768+b)*2048,
             sBeta[7], sG[7], sS0[7], sS1[7], sS2[7], sGam[7], red, t);

  // Pass 4: apply all 4 updates, write final memory
  mem_pass<4,0,0,0,false,true>(gmb, tile, slots, kr,kw,er,aw,sKn, racc,
                               (float4*)(out + O_MEM) + (size_t)b*32768, t);
}

// ---------------- launch ----------------

extern "C" void kernel_launch(void* const* d_in, const int* in_sizes, int n_in,
                              void* d_out, int out_size, void* d_ws, size_t ws_size,
                              hipStream_t stream) {
  (void)in_sizes; (void)n_in; (void)out_size; (void)ws_size;
  const float* ext    = (const float*)d_in[0];
  const float* prd    = (const float*)d_in[1];
  const float* prw    = (const float*)d_in[2];
  const float* pww    = (const float*)d_in[3];
  const float* mem0   = (const float*)d_in[4];
  const float* ctrlW  = (const float*)d_in[5];
  const float* ctrlB  = (const float*)d_in[6];
  const float* readW  = (const float*)d_in[7];
  const float* readB  = (const float*)d_in[8];
  const float* writeW = (const float*)d_in[9];
  const float* writeB = (const float*)d_in[10];
  const float* outW   = (const float*)d_in[11];
  const float* outB   = (const float*)d_in[12];
  float* out = (float*)d_out;
  float* ws  = (float*)d_ws;
  float* ctrl = ws;                 // 131072
  float* rp   = ws + 131072;        // 71680
  float* wp   = rp + 71680;         // 202752

  k1_ctrl<<<128,256,0,stream>>>(ext, prd, ctrlW, ctrlB, ctrl);
  k2_proj<<<128,512,0,stream>>>(ctrl, readW, readB, writeW, writeB, rp, wp);
  mega_kernel<<<256,256,0,stream>>>(mem0, prw, pww, rp, wp, out);
  k3_out<<<128,256,0,stream>>>(ctrl, outW, outB, out);
}

// Round 2
// 609.932 us; speedup vs baseline: 1.2892x; 1.2892x over previous
//
#include <hip/hip_runtime.h>
#include <math.h>

#define EPSV 1e-8f

// d_out layout (floats): ntm_out[0], memory[65536], read_out[33619968],
// new_read_w[33685504], new_write_w[35782656]
#define O_MEM 65536
#define O_RO  33619968
#define O_NRW 33685504
#define O_NWW 35782656

__device__ __forceinline__ float sp_(float x){ return fmaxf(x,0.f) + log1pf(expf(-fabsf(x))); }
__device__ __forceinline__ float sg_(float x){ return 1.f/(1.f+expf(-x)); }

// ---------------- fused controller + projections ----------------
// ctrl = concat(ext,prd) @ ctrl_W + b ; rp/wp = ctrl @ {read,write}_W + b
__global__ void k_proj(const float* __restrict__ ext, const float* __restrict__ prd,
                       const float* __restrict__ cW, const float* __restrict__ cB,
                       const float* __restrict__ rW, const float* __restrict__ rB,
                       const float* __restrict__ wW, const float* __restrict__ wB,
                       float* __restrict__ ctrl, float* __restrict__ rp, float* __restrict__ wp){
  __shared__ float ins[2][512];
  __shared__ float cs[2][512];
  int t = threadIdx.x; int b0 = blockIdx.x*2;
  for (int i=t; i<1024; i+=512){
    int bb=i>>9, i2=i&511;
    ins[bb][i2] = (i2<256)? ext[(b0+bb)*256+i2] : prd[(b0+bb)*256+(i2-256)];
  }
  __syncthreads();
  { // controller GEMM: thread t owns column t for both batches
    float a0=0.f, a1=0.f;
    for (int i=0;i<512;i++){
      float w = cW[i*512+t];
      a0 = fmaf(ins[0][i],w,a0); a1 = fmaf(ins[1][i],w,a1);
    }
    float bv = cB[t];
    a0 += bv; a1 += bv;
    cs[0][t]=a0; cs[1][t]=a1;
    ctrl[(size_t)b0*512+t]    = a0;
    ctrl[(size_t)(b0+1)*512+t]= a1;
  }
  __syncthreads();
  for (int c = t; c < 1072; c += 512){
    const float* Wc; int stride; float bv; float* dst0; float* dst1;
    if (c < 280){
      int h=c/70, j=c%70;
      Wc = rW + (size_t)h*512*70 + j; stride = 70; bv = rB[h*70+j];
      dst0 = rp + ((size_t)(h*256)+b0)*70 + j; dst1 = dst0 + 70;
    } else {
      int c2=c-280; int h=c2/198, j=c2%198;
      Wc = wW + (size_t)h*512*198 + j; stride = 198; bv = wB[h*198+j];
      dst0 = wp + ((size_t)(h*256)+b0)*198 + j; dst1 = dst0 + 198;
    }
    float a0=0.f,a1=0.f;
    for (int i=0;i<512;i++){
      float w = Wc[(size_t)i*stride];
      a0 = fmaf(cs[0][i],w,a0); a1 = fmaf(cs[1][i],w,a1);
    }
    *dst0 = a0+bv; *dst1 = a1+bv;
  }
}

// ntm_out = concat(ctrl, read_out) @ out_W + out_b
__global__ void k3_out(const float* __restrict__ ctrl, const float* __restrict__ oW,
                       const float* __restrict__ oB, float* __restrict__ out){
  __shared__ float cr[2][768];
  int t = threadIdx.x; int b0 = blockIdx.x*2;
  for (int i=t;i<1536;i+=256){
    int bb=i/768, i2=i%768;
    cr[bb][i2] = (i2<512) ? ctrl[(b0+bb)*512+i2] : out[O_RO + (b0+bb)*256 + (i2-512)];
  }
  __syncthreads();
  float a0=0.f,a1=0.f;
  for (int i=0;i<768;i++){
    float w = oW[i*256+t];
    a0=fmaf(cr[0][i],w,a0); a1=fmaf(cr[1][i],w,a1);
  }
  out[(size_t)b0*256 + t]     = a0 + oB[t];
  out[(size_t)(b0+1)*256 + t] = a1 + oB[t];
}

// ---------------- mega kernel (512 threads, barrier-free streaming passes) ----

__device__ __forceinline__ float blockMax(float v, float* red){
  #pragma unroll
  for (int o=32;o;o>>=1) v = fmaxf(v, __shfl_down(v,o,64));
  __syncthreads();
  if ((threadIdx.x & 63) == 0) red[threadIdx.x>>6] = v;
  __syncthreads();
  float m = red[0];
  #pragma unroll
  for (int i=1;i<8;i++) m = fmaxf(m, red[i]);
  return m;
}
__device__ __forceinline__ float blockSum(float v, float* red){
  #pragma unroll
  for (int o=32;o;o>>=1) v += __shfl_down(v,o,64);
  __syncthreads();
  if ((threadIdx.x & 63) == 0) red[threadIdx.x>>6] = v;
  __syncthreads();
  float s = red[0];
  #pragma unroll
  for (int i=1;i<8;i++) s += red[i];
  return s;
}

// NTM addressing over slot c[2048] (cos-sim on entry, final w on exit). 512 thr, 4/thread.
__device__ void addressing(float* c, const float* __restrict__ wprev, float* __restrict__ wout,
                           float beta, float g, float s0, float s1, float s2, float gam,
                           float* red, int t){
  int base = t*4;
  float lv[4];
  {
    float4 cv = *(const float4*)&c[base];
    lv[0]=beta*cv.x; lv[1]=beta*cv.y; lv[2]=beta*cv.z; lv[3]=beta*cv.w;
  }
  float mx = fmaxf(fmaxf(lv[0],lv[1]), fmaxf(lv[2],lv[3]));
  mx = blockMax(mx, red);
  float sm = 0.f;
  #pragma unroll
  for (int i=0;i<4;i++){ lv[i] = expf(lv[i]-mx); sm += lv[i]; }
  sm = blockSum(sm, red);
  float inv = 1.f/sm;
  float gi = 1.f - g;
  {
    float4 wp4 = *(const float4*)&wprev[base];
    lv[0] = g*lv[0]*inv + gi*wp4.x;
    lv[1] = g*lv[1]*inv + gi*wp4.y;
    lv[2] = g*lv[2]*inv + gi*wp4.z;
    lv[3] = g*lv[3]*inv + gi*wp4.w;
  }
  *(float4*)&c[base] = make_float4(lv[0],lv[1],lv[2],lv[3]);
  __syncthreads();
  float left  = c[(base+2047)&2047];
  float right = c[(base+4)&2047];
  __syncthreads();
  float pw[4]; float ps=0.f;
  #pragma unroll
  for (int i=0;i<4;i++){
    float wm1 = (i==0)? left  : lv[i-1];
    float wp1 = (i==3)? right : lv[i+1];
    float wsv = s0*wp1 + s1*lv[i] + s2*wm1;
    float p = expf(gam * logf(wsv + EPSV));
    pw[i]=p; ps+=p;
  }
  ps = blockSum(ps, red);
  float invp = 1.f/ps;
  float4 wo = make_float4(pw[0]*invp, pw[1]*invp, pw[2]*invp, pw[3]*invp);
  *(float4*)&c[base] = wo;
  *(float4*)&wout[base] = wo;
  __syncthreads();
}

// Streaming cos pass: 4 lanes/row, 128 rows/iter, 16 iters, NO internal barriers.
// Replays NUPD write updates in registers, computes norm + NCOS cos sims.
template<int NUPD, int NCOS, int KS0>
__device__ __forceinline__ void cos_pass(const float* __restrict__ gmb,
    float (*slots)[2048], const float* __restrict__ kr, const float* __restrict__ kw,
    const float* __restrict__ er, const float* __restrict__ aw,
    const float* __restrict__ kn, int t)
{
  const int row0 = t>>2, q = t&3, cb = q<<4;
  float4 kk[NCOS][4];
  float knl[NCOS];
  #pragma unroll
  for (int c=0;c<NCOS;c++){
    const int ks = (NCOS==5)? c : KS0;
    const float* kb = (ks<4)? (kr + ks*64) : (kw + (ks-4)*64);
    #pragma unroll
    for (int j=0;j<4;j++) kk[c][j] = *(const float4*)&kb[cb + 4*j];
    knl[c] = kn[ks];
  }
  float4 ee[NUPD>0?NUPD:1][4], aa[NUPD>0?NUPD:1][4];
  #pragma unroll
  for (int h=0;h<NUPD;h++){
    #pragma unroll
    for (int j=0;j<4;j++){
      ee[h][j] = *(const float4*)&er[h*64+cb+4*j];
      aa[h][j] = *(const float4*)&aw[h*64+cb+4*j];
    }
  }
  #pragma unroll 4
  for (int it=0; it<16; ++it){
    const int row = (it<<7) + row0;
    const float4* src = (const float4*)(gmb + ((size_t)row<<6) + cb);
    float4 v[4];
    #pragma unroll
    for (int j=0;j<4;j++) v[j] = src[j];
    #pragma unroll
    for (int h=0;h<NUPD;h++){
      float w = slots[4+h][row];
      #pragma unroll
      for (int j=0;j<4;j++){
        v[j].x = fmaf(-w, fmaf(v[j].x, ee[h][j].x, -aa[h][j].x), v[j].x);
        v[j].y = fmaf(-w, fmaf(v[j].y, ee[h][j].y, -aa[h][j].y), v[j].y);
        v[j].z = fmaf(-w, fmaf(v[j].z, ee[h][j].z, -aa[h][j].z), v[j].z);
        v[j].w = fmaf(-w, fmaf(v[j].w, ee[h][j].w, -aa[h][j].w), v[j].w);
      }
    }
    float nrm = 0.f;
    float acc[NCOS];
    #pragma unroll
    for (int c=0;c<NCOS;c++) acc[c]=0.f;
    #pragma unroll
    for (int j=0;j<4;j++){
      nrm = fmaf(v[j].x,v[j].x, fmaf(v[j].y,v[j].y, fmaf(v[j].z,v[j].z, fmaf(v[j].w,v[j].w, nrm))));
      #pragma unroll
      for (int c=0;c<NCOS;c++){
        acc[c] = fmaf(v[j].x,kk[c][j].x, fmaf(v[j].y,kk[c][j].y,
                  fmaf(v[j].z,kk[c][j].z, fmaf(v[j].w,kk[c][j].w, acc[c]))));
      }
    }
    nrm += __shfl_xor(nrm,1); nrm += __shfl_xor(nrm,2);
    #pragma unroll
    for (int c=0;c<NCOS;c++){ acc[c] += __shfl_xor(acc[c],1); acc[c] += __shfl_xor(acc[c],2); }
    float mn = sqrtf(nrm);
    if (NCOS==5){
      float av = acc[0], kv = knl[0];
      #pragma unroll
      for (int c=1;c<4;c++){ if (q==c){ av=acc[c]; kv=knl[c]; } }
      slots[q][row] = av/(mn*kv+EPSV);
      if (q==0) slots[4][row] = acc[4]/(mn*knl[4]+EPSV);
    } else {
      if (q==0) slots[KS0][row] = acc[0]/(mn*knl[0]+EPSV);
    }
  }
}

// Final pass: 8 lanes/row, 64 rows/iter, 32 iters. Accumulates reads on raw rows,
// applies all 4 updates, writes final memory. No internal barriers.
__device__ __forceinline__ void final_pass(const float* __restrict__ gmb,
    float (*slots)[2048], const float* __restrict__ er, const float* __restrict__ aw,
    float4 racc[4][2], float* __restrict__ gout, int t)
{
  const int row0 = t>>3, q = t&7, cb = q<<3;
  float4 ee[4][2], aa[4][2];
  #pragma unroll
  for (int h=0;h<4;h++){
    #pragma unroll
    for (int j=0;j<2;j++){
      ee[h][j] = *(const float4*)&er[h*64+cb+4*j];
      aa[h][j] = *(const float4*)&aw[h*64+cb+4*j];
    }
  }
  #pragma unroll 4
  for (int it=0; it<32; ++it){
    const int row = (it<<6) + row0;
    const float4* src = (const float4*)(gmb + ((size_t)row<<6) + cb);
    float4 v0 = src[0], v1 = src[1];
    #pragma unroll
    for (int h=0;h<4;h++){
      float wr = slots[h][row];
      racc[h][0].x = fmaf(wr, v0.x, racc[h][0].x);
      racc[h][0].y = fmaf(wr, v0.y, racc[h][0].y);
      racc[h][0].z = fmaf(wr, v0.z, racc[h][0].z);
      racc[h][0].w = fmaf(wr, v0.w, racc[h][0].w);
      racc[h][1].x = fmaf(wr, v1.x, racc[h][1].x);
      racc[h][1].y = fmaf(wr, v1.y, racc[h][1].y);
      racc[h][1].z = fmaf(wr, v1.z, racc[h][1].z);
      racc[h][1].w = fmaf(wr, v1.w, racc[h][1].w);
    }
    #pragma unroll
    for (int h=0;h<4;h++){
      float w = slots[4+h][row];
      v0.x = fmaf(-w, fmaf(v0.x, ee[h][0].x, -aa[h][0].x), v0.x);
      v0.y = fmaf(-w, fmaf(v0.y, ee[h][0].y, -aa[h][0].y), v0.y);
      v0.z = fmaf(-w, fmaf(v0.z, ee[h][0].z, -aa[h][0].z), v0.z);
      v0.w = fmaf(-w, fmaf(v0.w, ee[h][0].w, -aa[h][0].w), v0.w);
      v1.x = fmaf(-w, fmaf(v1.x, ee[h][1].x, -aa[h][1].x), v1.x);
      v1.y = fmaf(-w, fmaf(v1.y, ee[h][1].y, -aa[h][1].y), v1.y);
      v1.z = fmaf(-w, fmaf(v1.z, ee[h][1].z, -aa[h][1].z), v1.z);
      v1.w = fmaf(-w, fmaf(v1.w, ee[h][1].w, -aa[h][1].w), v1.w);
    }
    float4* dst = (float4*)(gout + ((size_t)row<<6) + cb);
    dst[0]=v0; dst[1]=v1;
  }
}

__global__ __launch_bounds__(512) void mega_kernel(
    const float* __restrict__ mem0, const float* __restrict__ prw, const float* __restrict__ pww,
    const float* __restrict__ rp, const float* __restrict__ wp, float* __restrict__ out)
{
  const int b = blockIdx.x, t = threadIdx.x;
  __shared__ float slots[8][2048];   // 64 KB: 0-3 cos_r->w_r ; 4-7 cos_w->w_w
  __shared__ float kr[256], kw[256], er[256], aw[256];
  __shared__ float sBeta[8], sG[8], sGam[8], sKn[8], sS0[8], sS1[8], sS2[8];
  __shared__ float red[8];

  if (t < 256){ // activations: idx 0-3 read heads, 4-7 write heads
    int h = t>>6, m = t&63;
    kr[t] = rp[((size_t)h*256 + b)*70 + m];
    const float* wph = wp + ((size_t)h*256 + b)*198;
    kw[t] = wph[m];
    er[t] = sg_(wph[70+m]);
    aw[t] = tanhf(wph[134+m]);
    if (t < 8){
      int hh = t & 3;
      const float* p = (t>=4) ? (wp + ((size_t)hh*256+b)*198) : (rp + ((size_t)hh*256+b)*70);
      sBeta[t] = sp_(p[64]);
      sG[t]    = sg_(p[65]);
      float a0=p[66], a1=p[67], a2=p[68];
      float mx = fmaxf(a0, fmaxf(a1,a2));
      float e0=expf(a0-mx), e1=expf(a1-mx), e2=expf(a2-mx);
      float inv = 1.f/(e0+e1+e2);
      sS0[t]=e0*inv; sS1[t]=e1*inv; sS2[t]=e2*inv;
      sGam[t]  = 1.f + sp_(p[69]);
    }
  }
  __syncthreads();
  if (t < 8){
    const float* kv = (t>=4) ? (kw + (t&3)*64) : (kr + (t&3)*64);
    float s=0.f;
    for (int m=0;m<64;m++) s = fmaf(kv[m],kv[m],s);
    sKn[t] = sqrtf(s);
  }
  __syncthreads();

  const float* gmb = mem0 + (size_t)b*131072;

  // Pass A: cos for read heads 0-3 (slots 0-3) + write head 0 (slot 4)
  cos_pass<0,5,0>(gmb, slots, kr,kw,er,aw,sKn, t);
  __syncthreads();
  #pragma unroll 1
  for (int h=0;h<4;h++)
    addressing(slots[h], prw + ((size_t)h*256+b)*2048, out + O_NRW + ((size_t)h*256+b)*2048,
               sBeta[h], sG[h], sS0[h], sS1[h], sS2[h], sGam[h], red, t);
  addressing(slots[4], pww + (size_t)b*2048, out + O_NWW + (size_t)b*2048,
             sBeta[4], sG[4], sS0[4], sS1[4], sS2[4], sGam[4], red, t);

  // Pass 1: update{0} -> cos_w1 (slot 5)
  cos_pass<1,1,5>(gmb, slots, kr,kw,er,aw,sKn, t);
  __syncthreads();
  addressing(slots[5], pww + ((size_t)256+b)*2048, out + O_NWW + ((size_t)256+b)*2048,
             sBeta[5], sG[5], sS0[5], sS1[5], sS2[5], sGam[5], red, t);

  // Pass 2: updates{0,1} -> cos_w2 (slot 6)
  cos_pass<2,1,6>(gmb, slots, kr,kw,er,aw,sKn, t);
  __syncthreads();
  addressing(slots[6], pww + ((size_t)512+b)*2048, out + O_NWW + ((size_t)512+b)*2048,
             sBeta[6], sG[6], sS0[6], sS1[6], sS2[6], sGam[6], red, t);

  // Pass 3: updates{0,1,2} -> cos_w3 (slot 7)
  cos_pass<3,1,7>(gmb, slots, kr,kw,er,aw,sKn, t);
  __syncthreads();
  addressing(slots[7], pww + ((size_t)768+b)*2048, out + O_NWW + ((size_t)768+b)*2048,
             sBeta[7], sG[7], sS0[7], sS1[7], sS2[7], sGam[7], red, t);

  // Final pass: reads on raw rows + all 4 updates + write memory
  float4 racc[4][2];
  #pragma unroll
  for (int h=0;h<4;h++){ racc[h][0]=make_float4(0,0,0,0); racc[h][1]=make_float4(0,0,0,0); }
  final_pass(gmb, slots, er, aw, racc, out + O_MEM + (size_t)b*131072, t);
  __syncthreads();

  // reads reduction: partials (row0=t>>3, q=t&7) over cols q*8..q*8+7
  {
    float* scr = (float*)slots;
    #pragma unroll 1
    for (int h=0;h<4;h++){
      *(float4*)&scr[t*8]   = racc[h][0];
      *(float4*)&scr[t*8+4] = racc[h][1];
      __syncthreads();
      if (t < 64){
        int qq = t>>3, c = t&7;
        float s = 0.f;
        for (int g=0; g<64; ++g) s += scr[g*512 + qq*8 + c + (g&0)];
        // note: thread index layout is t2 = g*8+qq -> scr[(g*8+qq)*8 + c]
        s = 0.f;
        for (int g=0; g<64; ++g) s += scr[(g*8+qq)*8 + c];
        out[O_RO + (size_t)b*256 + h*64 + t] = s;
      }
      __syncthreads();
    }
  }
}

// ---------------- launch ----------------

extern "C" void kernel_launch(void* const* d_in, const int* in_sizes, int n_in,
                              void* d_out, int out_size, void* d_ws, size_t ws_size,
                              hipStream_t stream) {
  (void)in_sizes; (void)n_in; (void)out_size; (void)ws_size;
  const float* ext    = (const float*)d_in[0];
  const float* prd    = (const float*)d_in[1];
  const float* prw    = (const float*)d_in[2];
  const float* pww    = (const float*)d_in[3];
  const float* mem0   = (const float*)d_in[4];
  const float* ctrlW  = (const float*)d_in[5];
  const float* ctrlB  = (const float*)d_in[6];
  const float* readW  = (const float*)d_in[7];
  const float* readB  = (const float*)d_in[8];
  const float* writeW = (const float*)d_in[9];
  const float* writeB = (const float*)d_in[10];
  const float* outW   = (const float*)d_in[11];
  const float* outB   = (const float*)d_in[12];
  float* out = (float*)d_out;
  float* ws  = (float*)d_ws;
  float* ctrl = ws;                 // 131072 floats
  float* rp   = ws + 131072;        // 71680
  float* wp   = rp + 71680;         // 202752

  k_proj<<<128,512,0,stream>>>(ext, prd, ctrlW, ctrlB, readW, readB, writeW, writeB, ctrl, rp, wp);
  mega_kernel<<<256,512,0,stream>>>(mem0, prw, pww, rp, wp, out);
  k3_out<<<128,256,0,stream>>>(ctrl, outW, outB, out);
}